// Round 10
// baseline (883.442 us; speedup 1.0000x reference)
//
#include <hip/hip_runtime.h>

#define DEVI __device__ __forceinline__
typedef unsigned long long u64;

static constexpr float BN_INV_F = 0.9999950000374997f; // 1/sqrt(1+1e-5), f32-rounded

// exact (non-contracted) squared distance, matching ((dx^2+dy^2)+dz^2) in f32
DEVI float d2rn(float ax, float ay, float az, float bx, float by, float bz) {
    float dx = __fsub_rn(ax, bx), dy = __fsub_rn(ay, by), dz = __fsub_rn(az, bz);
    return __fadd_rn(__fadd_rn(__fmul_rn(dx, dx), __fmul_rn(dy, dy)), __fmul_rn(dz, dz));
}

DEVI u64 shfl_xor_u64(u64 x, int m) {
    unsigned lo = (unsigned)x, hi = (unsigned)(x >> 32);
    lo = (unsigned)__shfl_xor((int)lo, m, 64);
    hi = (unsigned)__shfl_xor((int)hi, m, 64);
    return ((u64)hi << 32) | lo;
}
DEVI u64 umin64(u64 a, u64 b) { return a < b ? a : b; }
DEVI u64 umax64(u64 a, u64 b) { return a > b ? a : b; }

// ---------------- furthest point sampling (reg coords, split-track inner loop) -----
// selection semantics identical to packed-u64 version: per-lane candidates have
// strictly increasing point index, so strict > keeps the smallest index among ties;
// d2 >= 0 (no -0/NaN) so float-bit order == numeric order in the packed reduce.
template <int N, int NPOINT, int BS>
DEVI void fps_impl(const float* __restrict__ xyz, int* __restrict__ fidx) {
    constexpr int PPT = N / BS;
    constexpr int NW = BS / 64;
    __shared__ float4 xs4[N];                      // staged coords (q broadcast)
    __shared__ u64 wmax[2][NW > 1 ? NW : 1];
    const int t = threadIdx.x, b = blockIdx.x, lane = t & 63, wv = t >> 6;
    const float* xb = xyz + (size_t)b * N * 3;
    for (int p = t; p < N; p += BS)
        xs4[p] = make_float4(xb[p * 3], xb[p * 3 + 1], xb[p * 3 + 2], 0.f);
    if (t == 0) fidx[b * NPOINT] = 0;
    __syncthreads();
    // private coords + dist chain in registers (lane owns points i*BS + t)
    float px[PPT], py[PPT], pz[PPT], dist[PPT];
#pragma unroll
    for (int i = 0; i < PPT; ++i) {
        float4 v = xs4[i * BS + t];
        px[i] = v.x; py[i] = v.y; pz[i] = v.z;
        dist[i] = 1e10f;
    }
    float4 q0 = xs4[0];
    float qx = q0.x, qy = q0.y, qz = q0.z;
    for (int it = 1; it < NPOINT; ++it) {
        float bestd = -1.f;
        unsigned bestidx = 0u;
#pragma unroll
        for (int i = 0; i < PPT; ++i) {
            float d = d2rn(px[i], py[i], pz[i], qx, qy, qz);
            float nd = fminf(dist[i], d);
            dist[i] = nd;
            if (nd > bestd) { bestd = nd; bestidx = (unsigned)(i * BS + t); }
        }
        u64 best = ((u64)__float_as_uint(bestd) << 32) | (0xFFFFFFFFu - bestidx);
#pragma unroll
        for (int m = 1; m < 64; m <<= 1) best = umax64(best, shfl_xor_u64(best, m));
        if constexpr (NW > 1) {
            if (lane == 0) wmax[it & 1][wv] = best;
            __syncthreads();
            u64 m2 = wmax[it & 1][lane & (NW - 1)];
#pragma unroll
            for (int m = 1; m < NW; m <<= 1) m2 = umax64(m2, shfl_xor_u64(m2, m));
            best = m2;
        }
        int p = (int)(0xFFFFFFFFu - (unsigned)best);
        float4 qv = xs4[p];
        qx = qv.x; qy = qv.y; qz = qv.z;
        if (t == 0) fidx[b * NPOINT + it] = p;
    }
}

__global__ __launch_bounds__(256) void fps1_kernel(const float* __restrict__ x, int* __restrict__ f) { fps_impl<4096, 256, 256>(x, f); }
__global__ __launch_bounds__(64)  void fps2_kernel(const float* __restrict__ x, int* __restrict__ f) { fps_impl<256, 64, 64>(x, f); }
__global__ __launch_bounds__(64)  void fps3_kernel(const float* __restrict__ x, int* __restrict__ f) { fps_impl<64, 16, 64>(x, f); }

// ---------------- shared GEMM phase (TX=16 x TY=16 threads) ------------------------
// thread tile RT=TR/16 rows x NCOL cols (cols tx+16i). Xs float4-swizzled by ty&3.
// 8-k chunks, Ws double-buffer (stride 12 floats, 16B-aligned), reg prefetch early,
// ONE barrier per chunk. KMAIN = padded main-K (mult of 8), CIM = real main width,
// CIF = full W row stride, MOFF = W col offset of main block.
// MODE: 0 = BN+ReLU -> Xs (acc over all CC, in-place safe);
//       1 = (+bias)BN+ReLU -> gout rows stride OSTR;
//       2 = BN+ReLU + 16-row-group maxpool via LDS atomicMax (vals >= 0).
// SIDE: add 3 extra input cols (W cols SOFF..SOFF+2) from side[row*3+j] (MODE 0).
template <int TR, int XSTR, int KMAIN, int CIM, int CIF, int MOFF, int CO, int MODE,
          bool SIDE, int SOFF, int OSTR>
DEVI void gemm_phase(float* __restrict__ Xs, float* __restrict__ Ws,
                     const float* __restrict__ W,
                     const float* __restrict__ sA, const float* __restrict__ sB,
                     const float* __restrict__ fbias,
                     float* __restrict__ gout, int r0,
                     unsigned* __restrict__ mp, const float* __restrict__ side, int t) {
    constexpr int RT = TR / 16;
    constexpr int NCOL = (CO / 16 < 8) ? (CO / 16) : 8;
    constexpr int ROWS = 16 * NCOL;
    constexpr int CC = CO / ROWS;
    constexpr int NCH = KMAIN / 8;
    constexpr int NQ = CC * NCH;
    constexpr int PRE = ROWS / 32;       // ROWS*8/256
    constexpr int XSTR4 = XSTR / 4;
    constexpr int AC = (MODE == 0) ? CC : 1;
    const int tx = t & 15, ty = t >> 4;
    const int swz = ty & 3;
    float acc[AC][RT][NCOL];
    if constexpr (MODE == 0) {
#pragma unroll
        for (int a = 0; a < AC; ++a)
#pragma unroll
            for (int r = 0; r < RT; ++r)
#pragma unroll
                for (int i = 0; i < NCOL; ++i) acc[a][r][i] = 0.f;
    }
    float pre[PRE];
#pragma unroll
    for (int i = 0; i < PRE; ++i) {      // prefetch chunk 0 (cc=0,k0=0)
        int e = t + 256 * i, row = e >> 3, kk = e & 7;
        pre[i] = (kk < CIM) ? W[(size_t)row * CIF + MOFF + kk] : 0.f;
    }
#pragma unroll
    for (int i = 0; i < PRE; ++i) {      // prologue stage -> buffer 0
        int e = t + 256 * i;
        Ws[(e >> 3) * 12 + (e & 7)] = pre[i];
    }
#pragma unroll
    for (int cc = 0; cc < CC; ++cc) {
        if constexpr (MODE != 0) {
#pragma unroll
            for (int r = 0; r < RT; ++r)
#pragma unroll
                for (int i = 0; i < NCOL; ++i) acc[0][r][i] = 0.f;
        }
        for (int kc = 0; kc < NCH; ++kc) {
            const int qq = cc * NCH + kc, buf = kc & 1;
            __syncthreads();   // Ws[buf] staged & previous chunk's readers done
            if (qq + 1 < NQ) { // issue next chunk's global loads early
                const int cn = (qq + 1) / NCH, kn = ((qq + 1) % NCH) * 8;
#pragma unroll
                for (int i = 0; i < PRE; ++i) {
                    int e = t + 256 * i, row = e >> 3, k = kn + (e & 7);
                    pre[i] = (k < CIM) ? W[(size_t)(cn * ROWS + row) * CIF + MOFF + k] : 0.f;
                }
            }
            const float* wsb = Ws + buf * (ROWS * 12);
#pragma unroll
            for (int k4i = 0; k4i < 2; ++k4i) {
                const int c4 = kc * 2 + k4i;
                float4 wv[NCOL];
#pragma unroll
                for (int i = 0; i < NCOL; ++i)
                    wv[i] = *(const float4*)&wsb[(tx + 16 * i) * 12 + k4i * 4];
                float4 xv[RT];
#pragma unroll
                for (int r = 0; r < RT; ++r)
                    xv[r] = *(const float4*)&Xs[((ty * RT + r) * XSTR4 + (c4 ^ swz)) * 4];
#pragma unroll
                for (int r = 0; r < RT; ++r)
#pragma unroll
                    for (int i = 0; i < NCOL; ++i) {
                        const int a = (MODE == 0) ? cc : 0;
                        acc[a][r][i] = fmaf(xv[r].x, wv[i].x, acc[a][r][i]);
                        acc[a][r][i] = fmaf(xv[r].y, wv[i].y, acc[a][r][i]);
                        acc[a][r][i] = fmaf(xv[r].z, wv[i].z, acc[a][r][i]);
                        acc[a][r][i] = fmaf(xv[r].w, wv[i].w, acc[a][r][i]);
                    }
            }
            if (qq + 1 < NQ) {   // write-late into the other buffer
                float* wsn = Ws + (buf ^ 1) * (ROWS * 12);
#pragma unroll
                for (int i = 0; i < PRE; ++i) {
                    int e = t + 256 * i;
                    wsn[(e >> 3) * 12 + (e & 7)] = pre[i];
                }
            }
        }
        if constexpr (MODE == 1) {
#pragma unroll
            for (int i = 0; i < NCOL; ++i) {
                int c = cc * ROWS + tx + 16 * i;
                float bia = fbias ? fbias[c] : 0.f;
                float sc = sA[c] * BN_INV_F, be = sB[c];
#pragma unroll
                for (int r = 0; r < RT; ++r) {
                    float val = fmaxf(fmaf(acc[0][r][i] + bia, sc, be), 0.f);
                    gout[(size_t)(r0 + ty * RT + r) * OSTR + c] = val;
                }
            }
        } else if constexpr (MODE == 2) {
#pragma unroll
            for (int i = 0; i < NCOL; ++i) {
                int c = cc * ROWS + tx + 16 * i;
                float sc = sA[c] * BN_INV_F, bb = sB[c];
#pragma unroll
                for (int r = 0; r < RT; ++r) {
                    float val = fmaxf(fmaf(acc[0][r][i], sc, bb), 0.f);
                    atomicMax(&mp[((ty * RT + r) >> 4) * CO + c], __float_as_uint(val));
                }
            }
        }
    }
    if constexpr (MODE == 0) {
        if constexpr (SIDE) {   // add the 3 side input columns (before Xs rewrite)
#pragma unroll
            for (int cc = 0; cc < AC; ++cc)
#pragma unroll
                for (int i = 0; i < NCOL; ++i) {
                    int c = cc * ROWS + tx + 16 * i;
#pragma unroll
                    for (int j = 0; j < 3; ++j) {
                        float wj = W[(size_t)c * CIF + SOFF + j];
#pragma unroll
                        for (int r = 0; r < RT; ++r)
                            acc[cc][r][i] = fmaf(side[(ty * RT + r) * 3 + j], wj,
                                                 acc[cc][r][i]);
                    }
                }
        }
        __syncthreads();
#pragma unroll
        for (int cc = 0; cc < AC; ++cc)
#pragma unroll
            for (int i = 0; i < NCOL; ++i) {
                int c = cc * ROWS + tx + 16 * i;
                float sc = sA[c] * BN_INV_F, bb = sB[c];
#pragma unroll
                for (int r = 0; r < RT; ++r) {
                    int row = ty * RT + r;
                    Xs[(row * XSTR4 + ((c >> 2) ^ swz)) * 4 + (c & 3)] =
                        fmaxf(fmaf(acc[cc][r][i], sc, bb), 0.f);
                }
            }
        __syncthreads();
    }
}

// ---------------- SA module: wave ball-query + fill + GEMM MLP + maxpool -----------
template <int N, int S, int CIN, int C1, int C2, int TR, bool USE_SIDE>
DEVI void sa_impl(const float* __restrict__ xyz, const float* __restrict__ feats,
                  const int* __restrict__ fidx,
                  const float* __restrict__ w0, const float* __restrict__ g0, const float* __restrict__ b0,
                  const float* __restrict__ w1, const float* __restrict__ g1, const float* __restrict__ b1,
                  float* __restrict__ oxyz, float* __restrict__ ofeat, float r2) {
    constexpr int QPB = TR / 16;
    constexpr int CIF = 3 + CIN;
    constexpr int KMAIN = USE_SIDE ? CIN : 16;
    constexpr int XSTR = (KMAIN > C1) ? KMAIN : C1;
    constexpr int XSTR4 = XSTR / 4;
    constexpr int RT = TR / 16;
    __shared__ __align__(16) float Xs[TR * XSTR];
    __shared__ __align__(16) float Ws[2 * 128 * 12];
    __shared__ int ids[QPB][16];
    __shared__ float qp[QPB][3];
    __shared__ unsigned mp[QPB * C2];
    __shared__ float side[USE_SIDE ? TR * 3 : 4];
    const int t = threadIdx.x, lane = t & 63, wv = t >> 6;
    const int q0 = blockIdx.x * QPB;
    // ball query: one wave per query, ordered ballot emission, early exit (exact)
    for (int q = wv; q < QPB; q += 4) {
        const int sq = q0 + q, bb = sq / S;
        const float* xb = xyz + (size_t)bb * N * 3;
        const int qi = fidx[sq];
        const float qx = xb[qi * 3], qy = xb[qi * 3 + 1], qz = xb[qi * 3 + 2];
        if (lane == 0) {
            qp[q][0] = qx; qp[q][1] = qy; qp[q][2] = qz;
            float* op = oxyz + (size_t)sq * 3;
            op[0] = qx; op[1] = qy; op[2] = qz;
        }
        int base = 0;
        for (int seg = 0; seg < N; seg += 64) {
            const int p = seg + lane;
            float d = d2rn(xb[p * 3], xb[p * 3 + 1], xb[p * 3 + 2], qx, qy, qz);
            bool hit = d < r2;
            u64 mask = __ballot(hit);
            int before = (int)__popcll(mask & ((1ull << lane) - 1ull));
            if (hit && base + before < 16) ids[q][base + before] = p;
            base += (int)__popcll(mask);
            if (base >= 16) break;
        }
        if (lane == 0) {
            int cnt = base < 16 ? base : 16;
            int first = ids[q][0];
            for (int r = cnt; r < 16; ++r) ids[q][r] = first;
        }
    }
    __syncthreads();
    if constexpr (!USE_SIDE) {   // sa1: [dxyz3|feats3|pad..16]
        for (int e = t; e < TR * 16; e += 256) {
            int j = e >> 4, c = e & 15;
            int q = j >> 4, p = ids[q][j & 15];
            int bb = (q0 + q) / S;
            float v = 0.f;
            if (c < 3) v = __fsub_rn(xyz[((size_t)bb * N + p) * 3 + c], qp[q][c]);
            else if (c < 6) v = feats[((size_t)bb * N + p) * CIN + (c - 3)];
            Xs[(j * XSTR4 + ((c >> 2) ^ ((j / RT) & 3))) * 4 + (c & 3)] = v;
        }
    } else {                     // feats into Xs (float4), dxyz into side
        constexpr int C4N = CIN / 4;
        for (int e = t; e < TR * C4N; e += 256) {
            int j = e / C4N, c4 = e % C4N;
            int q = j >> 4, p = ids[q][j & 15];
            int bb = (q0 + q) / S;
            float4 v = *(const float4*)&feats[((size_t)bb * N + p) * CIN + c4 * 4];
            *(float4*)&Xs[(j * XSTR4 + (c4 ^ ((j / RT) & 3))) * 4] = v;
        }
        for (int e = t; e < TR * 3; e += 256) {
            int j = e / 3, c = e % 3;
            int q = j >> 4, p = ids[q][j & 15];
            int bb = (q0 + q) / S;
            side[e] = __fsub_rn(xyz[((size_t)bb * N + p) * 3 + c], qp[q][c]);
        }
    }
    for (int e = t; e < QPB * C2; e += 256) mp[e] = 0u;
    gemm_phase<TR, XSTR, KMAIN, (USE_SIDE ? CIN : 6), CIF, (USE_SIDE ? 3 : 0),
               C1, 0, USE_SIDE, 0, 0>(Xs, Ws, w0, g0, b0, nullptr, nullptr, 0,
                                      nullptr, side, t);
    gemm_phase<TR, XSTR, C1, C1, C1, 0, C2, 2, false, 0, 0>(
        Xs, Ws, w1, g1, b1, nullptr, nullptr, 0, mp, nullptr, t);
    __syncthreads();
    for (int e = t; e < QPB * C2; e += 256)
        ofeat[(size_t)q0 * C2 + e] = __uint_as_float(mp[e]);
}

#define SA_ARGS const float* __restrict__ xyz, const float* __restrict__ feats, \
                const int* __restrict__ fidx, \
                const float* __restrict__ w0, const float* __restrict__ g0, const float* __restrict__ b0, \
                const float* __restrict__ w1, const float* __restrict__ g1, const float* __restrict__ b1, \
                float* __restrict__ oxyz, float* __restrict__ ofeat, float r2
__global__ __launch_bounds__(256) void sa1_kernel(SA_ARGS) {
    sa_impl<4096, 256, 3, 64, 128, 64, false>(xyz, feats, fidx, w0, g0, b0, w1, g1, b1, oxyz, ofeat, r2);
}
__global__ __launch_bounds__(256) void sa2_kernel(SA_ARGS) {
    sa_impl<256, 64, 128, 128, 256, 64, true>(xyz, feats, fidx, w0, g0, b0, w1, g1, b1, oxyz, ofeat, r2);
}
__global__ __launch_bounds__(256) void sa3_kernel(SA_ARGS) {
    sa_impl<64, 16, 256, 256, 512, 16, true>(xyz, feats, fidx, w0, g0, b0, w1, g1, b1, oxyz, ofeat, r2);
}

// ---------------- FP module (fp2/fp3): wave 3-NN + interp + GEMM MLP ---------------
template <int M, int CK, int CU, int C1, int C2, int TR>
DEVI void fp_impl(const float* __restrict__ uxyz, const float* __restrict__ kxyz,
                  const float* __restrict__ ufeat, const float* __restrict__ kfeat,
                  const float* __restrict__ w0, const float* __restrict__ g0, const float* __restrict__ b0,
                  const float* __restrict__ w1, const float* __restrict__ g1, const float* __restrict__ b1,
                  float* __restrict__ out, int NU) {
    constexpr int CH = CK + CU;
    constexpr int XSTR = CH;
    constexpr int XSTR4 = XSTR / 4;
    constexpr int RT = TR / 16;
    __shared__ __align__(16) float Xs[TR * XSTR];
    __shared__ __align__(16) float Ws[2 * 128 * 12];
    __shared__ float kxs[M * 3];
    const int t = threadIdx.x, lane = t & 63, wv = t >> 6;
    const int r0 = blockIdx.x * TR;
    const int b = r0 / NU;
    for (int e = t; e < M * 3; e += 256) kxs[e] = kxyz[(size_t)b * M * 3 + e];
    __syncthreads();
    for (int j = wv; j < TR; j += 4) {
        const int r = r0 + j;
        const int sw = (j / RT) & 3;
        const float* up = uxyz + (size_t)r * 3;
        float ux = up[0], uy = up[1], uz = up[2];
        u64 a0 = ~0ull, a1 = ~0ull, a2 = ~0ull;
        for (int k = lane; k < M; k += 64) {
            float d = d2rn(kxs[k * 3], kxs[k * 3 + 1], kxs[k * 3 + 2], ux, uy, uz);
            u64 key = ((u64)__float_as_uint(d) << 32) | (unsigned)k;
            if (key < a0)      { a2 = a1; a1 = a0; a0 = key; }
            else if (key < a1) { a2 = a1; a1 = key; }
            else if (key < a2) { a2 = key; }
        }
#pragma unroll
        for (int m = 1; m < 64; m <<= 1) {
            u64 b0k = shfl_xor_u64(a0, m), b1k = shfl_xor_u64(a1, m), b2k = shfl_xor_u64(a2, m);
            u64 c0 = umin64(a0, b0k);
            u64 c1 = umin64(umax64(a0, b0k), umin64(a1, b1k));
            u64 c2 = umin64(umin64(umax64(a1, b0k), umax64(a0, b1k)), umin64(a2, b2k));
            a0 = c0; a1 = c1; a2 = c2;
        }
        int s0 = (int)(unsigned)a0, s1 = (int)(unsigned)a1, s2 = (int)(unsigned)a2;
        float d0 = __uint_as_float((unsigned)(a0 >> 32));
        float d1 = __uint_as_float((unsigned)(a1 >> 32));
        float dd2 = __uint_as_float((unsigned)(a2 >> 32));
        float wa = 1.0f / (d0 + 1e-8f), wb = 1.0f / (d1 + 1e-8f), wc = 1.0f / (dd2 + 1e-8f);
        float sum = (wa + wb) + wc;
        wa /= sum; wb /= sum; wc /= sum;
        const float* kb = kfeat + (size_t)b * M * CK;
        for (int c4 = lane; c4 < CK / 4; c4 += 64) {
            float4 va = *(const float4*)(kb + (size_t)s0 * CK + c4 * 4);
            float4 vb = *(const float4*)(kb + (size_t)s1 * CK + c4 * 4);
            float4 vc = *(const float4*)(kb + (size_t)s2 * CK + c4 * 4);
            float4 rr;
            rr.x = va.x * wa + vb.x * wb + vc.x * wc;
            rr.y = va.y * wa + vb.y * wb + vc.y * wc;
            rr.z = va.z * wa + vb.z * wb + vc.z * wc;
            rr.w = va.w * wa + vb.w * wb + vc.w * wc;
            *(float4*)&Xs[(j * XSTR4 + (c4 ^ sw)) * 4] = rr;
        }
        for (int c4 = CK / 4 + lane; c4 < CH / 4; c4 += 64) {
            float4 v = *(const float4*)&ufeat[(size_t)r * CU + (c4 * 4 - CK)];
            *(float4*)&Xs[(j * XSTR4 + (c4 ^ sw)) * 4] = v;
        }
    }
    gemm_phase<TR, XSTR, CH, CH, CH, 0, C1, 0, false, 0, 0>(
        Xs, Ws, w0, g0, b0, nullptr, nullptr, 0, nullptr, nullptr, t);
    gemm_phase<TR, XSTR, C1, C1, C1, 0, C2, 1, false, 0, C2>(
        Xs, Ws, w1, g1, b1, nullptr, out, r0, nullptr, nullptr, t);
}

#define FP_ARGS const float* __restrict__ uxyz, const float* __restrict__ kxyz, \
                const float* __restrict__ ufeat, const float* __restrict__ kfeat, \
                const float* __restrict__ w0, const float* __restrict__ g0, const float* __restrict__ b0, \
                const float* __restrict__ w1, const float* __restrict__ g1, const float* __restrict__ b1, \
                float* __restrict__ out, int NU
__global__ __launch_bounds__(256) void fp3_kernel(FP_ARGS) {
    fp_impl<16, 512, 256, 256, 256, 16>(uxyz, kxyz, ufeat, kfeat, w0, g0, b0, w1, g1, b1, out, NU);
}
__global__ __launch_bounds__(256) void fp2_kernel(FP_ARGS) {
    fp_impl<64, 256, 128, 128, 128, 16>(uxyz, kxyz, ufeat, kfeat, w0, g0, b0, w1, g1, b1, out, NU);
}

// ---------------- fp1 FUSED: 3-NN + interp + 131->128->128 + final 128->512 --------
// each block owns 128 d_out rows exclusively (no cross-block hazard); h2 stays in
// LDS between the MLP and the fused final layer (saves 66MB HBM round-trip + launch).
__global__ __launch_bounds__(256) void fp1_fused_kernel(
    const float* __restrict__ uxyz, const float* __restrict__ kxyz,
    const float* __restrict__ ufeat3, const float* __restrict__ kfeat,
    const float* __restrict__ w0, const float* __restrict__ g0, const float* __restrict__ b0,
    const float* __restrict__ w1, const float* __restrict__ g1, const float* __restrict__ b1,
    const float* __restrict__ fw, const float* __restrict__ fb,
    const float* __restrict__ fg, const float* __restrict__ fbe,
    float* __restrict__ out) {
    constexpr int TR = 128, M = 256, CK = 128;
    __shared__ __align__(16) float Xs[TR * 128];     // 64 KiB
    __shared__ __align__(16) float Ws[2 * 128 * 12]; // 12 KiB
    __shared__ float side[TR * 3];
    __shared__ float wgt2[TR * 2];
    __shared__ unsigned pidx[TR];
    const int t = threadIdx.x;
    const int r0 = blockIdx.x * TR;
    const int b = r0 >> 12;   // NU = 4096
    // side = raw 3-channel features (contiguous copy)
    for (int e = t; e < TR * 3; e += 256) side[e] = ufeat3[(size_t)r0 * 3 + e];
    // 3-NN: 4-lane group per row (exact order stats, same keys/merge as before)
    const int g = t >> 2, sub = t & 3;
    const float* kb3 = kxyz + (size_t)b * M * 3;
    for (int row = g; row < TR; row += 64) {
        const float* up = uxyz + (size_t)(r0 + row) * 3;
        float ux = up[0], uy = up[1], uz = up[2];
        u64 a0 = ~0ull, a1 = ~0ull, a2 = ~0ull;
        for (int k = sub; k < M; k += 4) {
            float d = d2rn(kb3[k * 3], kb3[k * 3 + 1], kb3[k * 3 + 2], ux, uy, uz);
            u64 key = ((u64)__float_as_uint(d) << 32) | (unsigned)k;
            if (key < a0)      { a2 = a1; a1 = a0; a0 = key; }
            else if (key < a1) { a2 = a1; a1 = key; }
            else if (key < a2) { a2 = key; }
        }
#pragma unroll
        for (int m = 1; m < 4; m <<= 1) {
            u64 b0k = shfl_xor_u64(a0, m), b1k = shfl_xor_u64(a1, m), b2k = shfl_xor_u64(a2, m);
            u64 c0 = umin64(a0, b0k);
            u64 c1 = umin64(umax64(a0, b0k), umin64(a1, b1k));
            u64 c2 = umin64(umin64(umax64(a1, b0k), umax64(a0, b1k)), umin64(a2, b2k));
            a0 = c0; a1 = c1; a2 = c2;
        }
        if (sub == 0) {
            unsigned s0 = (unsigned)a0 & 255u, s1 = (unsigned)a1 & 255u, s2 = (unsigned)a2 & 255u;
            float d0 = __uint_as_float((unsigned)(a0 >> 32));
            float d1 = __uint_as_float((unsigned)(a1 >> 32));
            float dd2 = __uint_as_float((unsigned)(a2 >> 32));
            float wa = 1.0f / (d0 + 1e-8f), wb = 1.0f / (d1 + 1e-8f), wc = 1.0f / (dd2 + 1e-8f);
            float sum = (wa + wb) + wc;
            wa /= sum; wb /= sum;
            pidx[row] = s0 | (s1 << 8) | (s2 << 16);
            wgt2[row * 2] = wa; wgt2[row * 2 + 1] = wb;
        }
    }
    __syncthreads();
    // interp fill, block-wide (Xs swizzled by (row/8)&3)
    const float* kfb = kfeat + (size_t)b * M * CK;
    for (int e = t; e < TR * 32; e += 256) {
        int j = e >> 5, c4 = e & 31;
        unsigned u = pidx[j];
        int s0 = u & 255, s1 = (u >> 8) & 255, s2 = (u >> 16) & 255;
        float wa = wgt2[j * 2], wb = wgt2[j * 2 + 1], wc = 1.0f - wa - wb;
        float4 va = *(const float4*)(kfb + (size_t)s0 * CK + c4 * 4);
        float4 vb = *(const float4*)(kfb + (size_t)s1 * CK + c4 * 4);
        float4 vc = *(const float4*)(kfb + (size_t)s2 * CK + c4 * 4);
        float4 rr;
        rr.x = va.x * wa + vb.x * wb + vc.x * wc;
        rr.y = va.y * wa + vb.y * wb + vc.y * wc;
        rr.z = va.z * wa + vb.z * wb + vc.z * wc;
        rr.w = va.w * wa + vb.w * wb + vc.w * wc;
        *(float4*)&Xs[(j * 32 + (c4 ^ ((j >> 3) & 3))) * 4] = rr;
    }
    gemm_phase<TR, 128, 128, 128, 131, 0, 128, 0, true, 128, 0>(
        Xs, Ws, w0, g0, b0, nullptr, nullptr, 0, nullptr, side, t);
    gemm_phase<TR, 128, 128, 128, 128, 0, 128, 0, false, 0, 0>(
        Xs, Ws, w1, g1, b1, nullptr, nullptr, 0, nullptr, nullptr, t);
    // fused final Conv1d(128->512)+bias+BN+ReLU straight to d_out (CC=4)
    gemm_phase<TR, 128, 128, 128, 128, 0, 512, 1, false, 0, 512>(
        Xs, Ws, fw, fg, fbe, fb, out, r0, nullptr, nullptr, t);
}

extern "C" void kernel_launch(void* const* d_in, const int* in_sizes, int n_in,
                              void* d_out, int out_size, void* d_ws, size_t ws_size,
                              hipStream_t stream) {
    (void)in_sizes; (void)n_in; (void)out_size; (void)ws_size;
    const float* xyz   = (const float*)d_in[0];
    const float* feats = (const float*)d_in[1];  // [B,N,3] point-major
    const float* sa1_w0 = (const float*)d_in[2];
    const float* sa1_g0 = (const float*)d_in[3];
    const float* sa1_b0 = (const float*)d_in[4];
    const float* sa1_w1 = (const float*)d_in[5];
    const float* sa1_g1 = (const float*)d_in[6];
    const float* sa1_b1 = (const float*)d_in[7];
    const float* sa2_w0 = (const float*)d_in[8];
    const float* sa2_g0 = (const float*)d_in[9];
    const float* sa2_b0 = (const float*)d_in[10];
    const float* sa2_w1 = (const float*)d_in[11];
    const float* sa2_g1 = (const float*)d_in[12];
    const float* sa2_b1 = (const float*)d_in[13];
    const float* sa3_w0 = (const float*)d_in[14];
    const float* sa3_g0 = (const float*)d_in[15];
    const float* sa3_b0 = (const float*)d_in[16];
    const float* sa3_w1 = (const float*)d_in[17];
    const float* sa3_g1 = (const float*)d_in[18];
    const float* sa3_b1 = (const float*)d_in[19];
    const float* fp3_w0 = (const float*)d_in[20];
    const float* fp3_g0 = (const float*)d_in[21];
    const float* fp3_b0 = (const float*)d_in[22];
    const float* fp3_w1 = (const float*)d_in[23];
    const float* fp3_g1 = (const float*)d_in[24];
    const float* fp3_b1 = (const float*)d_in[25];
    const float* fp2_w0 = (const float*)d_in[26];
    const float* fp2_g0 = (const float*)d_in[27];
    const float* fp2_b0 = (const float*)d_in[28];
    const float* fp2_w1 = (const float*)d_in[29];
    const float* fp2_g1 = (const float*)d_in[30];
    const float* fp2_b1 = (const float*)d_in[31];
    const float* fp1_w0 = (const float*)d_in[32];
    const float* fp1_g0 = (const float*)d_in[33];
    const float* fp1_b0 = (const float*)d_in[34];
    const float* fp1_w1 = (const float*)d_in[35];
    const float* fp1_g1 = (const float*)d_in[36];
    const float* fp1_b1 = (const float*)d_in[37];
    const float* fin_w  = (const float*)d_in[38];
    const float* fin_b  = (const float*)d_in[39];
    const float* fin_g  = (const float*)d_in[40];
    const float* fin_be = (const float*)d_in[41];

    float* ws = (float*)d_ws;
    float* l1x  = ws;                 // 16*256*3    = 12288
    float* l1f  = l1x + 12288;        // 16*256*128  = 524288
    float* l2x  = l1f + 524288;       // 16*64*3     = 3072
    float* l2f  = l2x + 3072;         // 16*64*256   = 262144
    float* l3x  = l2f + 262144;       // 16*16*3     = 768
    float* l3f  = l3x + 768;          // 16*16*512   = 131072
    float* l2fb = l3f + 131072;       // 16*64*256   = 262144
    float* l1fb = l2fb + 262144;      // 16*256*128  = 524288
    int* fidx1 = (int*)(l1fb + 524288);  // 16*256
    int* fidx2 = fidx1 + 4096;           // 16*64
    int* fidx3 = fidx2 + 1024;           // 16*16

    const float R2_1 = (float)(0.04 * 0.04);
    const float R2_2 = (float)(0.08 * 0.08);
    const float R2_3 = (float)(0.16 * 0.16);

    fps1_kernel<<<16, 256, 0, stream>>>(xyz, fidx1);
    sa1_kernel<<<1024, 256, 0, stream>>>(
        xyz, feats, fidx1, sa1_w0, sa1_g0, sa1_b0, sa1_w1, sa1_g1, sa1_b1,
        l1x, l1f, R2_1);

    fps2_kernel<<<16, 64, 0, stream>>>(l1x, fidx2);
    sa2_kernel<<<256, 256, 0, stream>>>(
        l1x, l1f, fidx2, sa2_w0, sa2_g0, sa2_b0, sa2_w1, sa2_g1, sa2_b1,
        l2x, l2f, R2_2);

    fps3_kernel<<<16, 64, 0, stream>>>(l2x, fidx3);
    sa3_kernel<<<256, 256, 0, stream>>>(
        l2x, l2f, fidx3, sa3_w0, sa3_g0, sa3_b0, sa3_w1, sa3_g1, sa3_b1,
        l3x, l3f, R2_3);

    // FP3: unk=l2 (1024 rows), kn=l3 (M=16), 768 -> 256 -> 256
    fp3_kernel<<<64, 256, 0, stream>>>(
        l2x, l3x, l2f, l3f, fp3_w0, fp3_g0, fp3_b0, fp3_w1, fp3_g1, fp3_b1,
        l2fb, 64);

    // FP2: unk=l1 (4096 rows), kn=l2 (M=64), 384 -> 128 -> 128
    fp2_kernel<<<256, 256, 0, stream>>>(
        l1x, l2x, l1f, l2fb, fp2_w0, fp2_g0, fp2_b0, fp2_w1, fp2_g1, fp2_b1,
        l1fb, 256);

    // FP1 fused: 131 -> 128 -> 128 -> 512 (+bias+BN+ReLU) straight to d_out
    fp1_fused_kernel<<<512, 256, 0, stream>>>(
        xyz, l1x, feats, l1fb, fp1_w0, fp1_g0, fp1_b0, fp1_w1, fp1_g1, fp1_b1,
        fin_w, fin_b, fin_g, fin_be, (float*)d_out);
}

// Round 11
// 805.043 us; speedup vs baseline: 1.0974x; 1.0974x over previous
//
#include <hip/hip_runtime.h>

#define DEVI __device__ __forceinline__
typedef unsigned long long u64;

static constexpr float BN_INV_F = 0.9999950000374997f; // 1/sqrt(1+1e-5), f32-rounded

// exact (non-contracted) squared distance, matching ((dx^2+dy^2)+dz^2) in f32
DEVI float d2rn(float ax, float ay, float az, float bx, float by, float bz) {
    float dx = __fsub_rn(ax, bx), dy = __fsub_rn(ay, by), dz = __fsub_rn(az, bz);
    return __fadd_rn(__fadd_rn(__fmul_rn(dx, dx), __fmul_rn(dy, dy)), __fmul_rn(dz, dz));
}

DEVI u64 shfl_xor_u64(u64 x, int m) {
    unsigned lo = (unsigned)x, hi = (unsigned)(x >> 32);
    lo = (unsigned)__shfl_xor((int)lo, m, 64);
    hi = (unsigned)__shfl_xor((int)hi, m, 64);
    return ((u64)hi << 32) | lo;
}
DEVI u64 umin64(u64 a, u64 b) { return a < b ? a : b; }
DEVI u64 umax64(u64 a, u64 b) { return a > b ? a : b; }

// ---------------- furthest point sampling (reg coords, split-track inner loop) -----
// selection semantics identical to packed-u64 version: per-lane candidates have
// strictly increasing point index, so strict > keeps the smallest index among ties;
// d2 >= 0 (no -0/NaN) so float-bit order == numeric order in the packed reduce.
template <int N, int NPOINT, int BS>
DEVI void fps_impl(const float* __restrict__ xyz, int* __restrict__ fidx) {
    constexpr int PPT = N / BS;
    constexpr int NW = BS / 64;
    __shared__ float4 xs4[N];                      // staged coords (q broadcast)
    __shared__ u64 wmax[2][NW > 1 ? NW : 1];
    const int t = threadIdx.x, b = blockIdx.x, lane = t & 63, wv = t >> 6;
    const float* xb = xyz + (size_t)b * N * 3;
    for (int p = t; p < N; p += BS)
        xs4[p] = make_float4(xb[p * 3], xb[p * 3 + 1], xb[p * 3 + 2], 0.f);
    if (t == 0) fidx[b * NPOINT] = 0;
    __syncthreads();
    // private coords + dist chain in registers (lane owns points i*BS + t)
    float px[PPT], py[PPT], pz[PPT], dist[PPT];
#pragma unroll
    for (int i = 0; i < PPT; ++i) {
        float4 v = xs4[i * BS + t];
        px[i] = v.x; py[i] = v.y; pz[i] = v.z;
        dist[i] = 1e10f;
    }
    float4 q0 = xs4[0];
    float qx = q0.x, qy = q0.y, qz = q0.z;
    for (int it = 1; it < NPOINT; ++it) {
        float bestd = -1.f;
        unsigned bestidx = 0u;
#pragma unroll
        for (int i = 0; i < PPT; ++i) {
            float d = d2rn(px[i], py[i], pz[i], qx, qy, qz);
            float nd = fminf(dist[i], d);
            dist[i] = nd;
            if (nd > bestd) { bestd = nd; bestidx = (unsigned)(i * BS + t); }
        }
        u64 best = ((u64)__float_as_uint(bestd) << 32) | (0xFFFFFFFFu - bestidx);
#pragma unroll
        for (int m = 1; m < 64; m <<= 1) best = umax64(best, shfl_xor_u64(best, m));
        if constexpr (NW > 1) {
            if (lane == 0) wmax[it & 1][wv] = best;
            __syncthreads();
            u64 m2 = wmax[it & 1][lane & (NW - 1)];
#pragma unroll
            for (int m = 1; m < NW; m <<= 1) m2 = umax64(m2, shfl_xor_u64(m2, m));
            best = m2;
        }
        int p = (int)(0xFFFFFFFFu - (unsigned)best);
        float4 qv = xs4[p];
        qx = qv.x; qy = qv.y; qz = qv.z;
        if (t == 0) fidx[b * NPOINT + it] = p;
    }
}

__global__ __launch_bounds__(256) void fps1_kernel(const float* __restrict__ x, int* __restrict__ f) { fps_impl<4096, 256, 256>(x, f); }
__global__ __launch_bounds__(64)  void fps2_kernel(const float* __restrict__ x, int* __restrict__ f) { fps_impl<256, 64, 64>(x, f); }
__global__ __launch_bounds__(64)  void fps3_kernel(const float* __restrict__ x, int* __restrict__ f) { fps_impl<64, 16, 64>(x, f); }

// ---------------- shared GEMM phase (TX=16 x TY=16 threads) ------------------------
// thread tile RT=TR/16 rows x NCOL cols (cols tx+16i). Xs float4-swizzled by ty&3.
// 8-k chunks, Ws double-buffer (stride 12 floats, 16B-aligned), reg prefetch early,
// ONE barrier per chunk. KMAIN = padded main-K (mult of 8), CIM = real main width,
// CIF = full W row stride, MOFF = W col offset of main block.
// MODE: 0 = BN+ReLU -> Xs (acc over all CC, in-place safe);
//       1 = (+bias)BN+ReLU -> gout rows stride OSTR;
//       2 = BN+ReLU + 16-row-group maxpool via LDS atomicMax (vals >= 0).
// SIDE: add 3 extra input cols (W cols SOFF..SOFF+2) from side[row*3+j] (MODE 0).
template <int TR, int XSTR, int KMAIN, int CIM, int CIF, int MOFF, int CO, int MODE,
          bool SIDE, int SOFF, int OSTR>
DEVI void gemm_phase(float* __restrict__ Xs, float* __restrict__ Ws,
                     const float* __restrict__ W,
                     const float* __restrict__ sA, const float* __restrict__ sB,
                     const float* __restrict__ fbias,
                     float* __restrict__ gout, int r0,
                     unsigned* __restrict__ mp, const float* __restrict__ side, int t) {
    constexpr int RT = TR / 16;
    constexpr int NCOL = (CO / 16 < 8) ? (CO / 16) : 8;
    constexpr int ROWS = 16 * NCOL;
    constexpr int CC = CO / ROWS;
    constexpr int NCH = KMAIN / 8;
    constexpr int NQ = CC * NCH;
    constexpr int PRE = ROWS / 32;       // ROWS*8/256
    constexpr int XSTR4 = XSTR / 4;
    constexpr int AC = (MODE == 0) ? CC : 1;
    const int tx = t & 15, ty = t >> 4;
    const int swz = ty & 3;
    float acc[AC][RT][NCOL];
    if constexpr (MODE == 0) {
#pragma unroll
        for (int a = 0; a < AC; ++a)
#pragma unroll
            for (int r = 0; r < RT; ++r)
#pragma unroll
                for (int i = 0; i < NCOL; ++i) acc[a][r][i] = 0.f;
    }
    float pre[PRE];
#pragma unroll
    for (int i = 0; i < PRE; ++i) {      // prefetch chunk 0 (cc=0,k0=0)
        int e = t + 256 * i, row = e >> 3, kk = e & 7;
        pre[i] = (kk < CIM) ? W[(size_t)row * CIF + MOFF + kk] : 0.f;
    }
#pragma unroll
    for (int i = 0; i < PRE; ++i) {      // prologue stage -> buffer 0
        int e = t + 256 * i;
        Ws[(e >> 3) * 12 + (e & 7)] = pre[i];
    }
#pragma unroll
    for (int cc = 0; cc < CC; ++cc) {
        if constexpr (MODE != 0) {
#pragma unroll
            for (int r = 0; r < RT; ++r)
#pragma unroll
                for (int i = 0; i < NCOL; ++i) acc[0][r][i] = 0.f;
        }
        for (int kc = 0; kc < NCH; ++kc) {
            const int qq = cc * NCH + kc, buf = kc & 1;
            __syncthreads();   // Ws[buf] staged & previous chunk's readers done
            if (qq + 1 < NQ) { // issue next chunk's global loads early
                const int cn = (qq + 1) / NCH, kn = ((qq + 1) % NCH) * 8;
#pragma unroll
                for (int i = 0; i < PRE; ++i) {
                    int e = t + 256 * i, row = e >> 3, k = kn + (e & 7);
                    pre[i] = (k < CIM) ? W[(size_t)(cn * ROWS + row) * CIF + MOFF + k] : 0.f;
                }
            }
            const float* wsb = Ws + buf * (ROWS * 12);
#pragma unroll
            for (int k4i = 0; k4i < 2; ++k4i) {
                const int c4 = kc * 2 + k4i;
                float4 wv[NCOL];
#pragma unroll
                for (int i = 0; i < NCOL; ++i)
                    wv[i] = *(const float4*)&wsb[(tx + 16 * i) * 12 + k4i * 4];
                float4 xv[RT];
#pragma unroll
                for (int r = 0; r < RT; ++r)
                    xv[r] = *(const float4*)&Xs[((ty * RT + r) * XSTR4 + (c4 ^ swz)) * 4];
#pragma unroll
                for (int r = 0; r < RT; ++r)
#pragma unroll
                    for (int i = 0; i < NCOL; ++i) {
                        const int a = (MODE == 0) ? cc : 0;
                        acc[a][r][i] = fmaf(xv[r].x, wv[i].x, acc[a][r][i]);
                        acc[a][r][i] = fmaf(xv[r].y, wv[i].y, acc[a][r][i]);
                        acc[a][r][i] = fmaf(xv[r].z, wv[i].z, acc[a][r][i]);
                        acc[a][r][i] = fmaf(xv[r].w, wv[i].w, acc[a][r][i]);
                    }
            }
            if (qq + 1 < NQ) {   // write-late into the other buffer
                float* wsn = Ws + (buf ^ 1) * (ROWS * 12);
#pragma unroll
                for (int i = 0; i < PRE; ++i) {
                    int e = t + 256 * i;
                    wsn[(e >> 3) * 12 + (e & 7)] = pre[i];
                }
            }
        }
        if constexpr (MODE == 1) {
#pragma unroll
            for (int i = 0; i < NCOL; ++i) {
                int c = cc * ROWS + tx + 16 * i;
                float bia = fbias ? fbias[c] : 0.f;
                float sc = sA[c] * BN_INV_F, be = sB[c];
#pragma unroll
                for (int r = 0; r < RT; ++r) {
                    float val = fmaxf(fmaf(acc[0][r][i] + bia, sc, be), 0.f);
                    gout[(size_t)(r0 + ty * RT + r) * OSTR + c] = val;
                }
            }
        } else if constexpr (MODE == 2) {
#pragma unroll
            for (int i = 0; i < NCOL; ++i) {
                int c = cc * ROWS + tx + 16 * i;
                float sc = sA[c] * BN_INV_F, bb = sB[c];
#pragma unroll
                for (int r = 0; r < RT; ++r) {
                    float val = fmaxf(fmaf(acc[0][r][i], sc, bb), 0.f);
                    atomicMax(&mp[((ty * RT + r) >> 4) * CO + c], __float_as_uint(val));
                }
            }
        }
    }
    if constexpr (MODE == 0) {
        if constexpr (SIDE) {   // add the 3 side input columns (before Xs rewrite)
#pragma unroll
            for (int cc = 0; cc < AC; ++cc)
#pragma unroll
                for (int i = 0; i < NCOL; ++i) {
                    int c = cc * ROWS + tx + 16 * i;
#pragma unroll
                    for (int j = 0; j < 3; ++j) {
                        float wj = W[(size_t)c * CIF + SOFF + j];
#pragma unroll
                        for (int r = 0; r < RT; ++r)
                            acc[cc][r][i] = fmaf(side[(ty * RT + r) * 3 + j], wj,
                                                 acc[cc][r][i]);
                    }
                }
        }
        __syncthreads();
#pragma unroll
        for (int cc = 0; cc < AC; ++cc)
#pragma unroll
            for (int i = 0; i < NCOL; ++i) {
                int c = cc * ROWS + tx + 16 * i;
                float sc = sA[c] * BN_INV_F, bb = sB[c];
#pragma unroll
                for (int r = 0; r < RT; ++r) {
                    int row = ty * RT + r;
                    Xs[(row * XSTR4 + ((c >> 2) ^ swz)) * 4 + (c & 3)] =
                        fmaxf(fmaf(acc[cc][r][i], sc, bb), 0.f);
                }
            }
        __syncthreads();
    }
}

// ---------------- SA module: wave ball-query + fill + GEMM MLP + maxpool -----------
template <int N, int S, int CIN, int C1, int C2, int TR, bool USE_SIDE>
DEVI void sa_impl(const float* __restrict__ xyz, const float* __restrict__ feats,
                  const int* __restrict__ fidx,
                  const float* __restrict__ w0, const float* __restrict__ g0, const float* __restrict__ b0,
                  const float* __restrict__ w1, const float* __restrict__ g1, const float* __restrict__ b1,
                  float* __restrict__ oxyz, float* __restrict__ ofeat, float r2) {
    constexpr int QPB = TR / 16;
    constexpr int CIF = 3 + CIN;
    constexpr int KMAIN = USE_SIDE ? CIN : 16;
    constexpr int XSTR = (KMAIN > C1) ? KMAIN : C1;
    constexpr int XSTR4 = XSTR / 4;
    constexpr int RT = TR / 16;
    __shared__ __align__(16) float Xs[TR * XSTR];
    __shared__ __align__(16) float Ws[2 * 128 * 12];
    __shared__ int ids[QPB][16];
    __shared__ float qp[QPB][3];
    __shared__ unsigned mp[QPB * C2];
    __shared__ float side[USE_SIDE ? TR * 3 : 4];
    const int t = threadIdx.x, lane = t & 63, wv = t >> 6;
    const int q0 = blockIdx.x * QPB;
    // ball query: one wave per query, ordered ballot emission, early exit (exact)
    for (int q = wv; q < QPB; q += 4) {
        const int sq = q0 + q, bb = sq / S;
        const float* xb = xyz + (size_t)bb * N * 3;
        const int qi = fidx[sq];
        const float qx = xb[qi * 3], qy = xb[qi * 3 + 1], qz = xb[qi * 3 + 2];
        if (lane == 0) {
            qp[q][0] = qx; qp[q][1] = qy; qp[q][2] = qz;
            float* op = oxyz + (size_t)sq * 3;
            op[0] = qx; op[1] = qy; op[2] = qz;
        }
        int base = 0;
        for (int seg = 0; seg < N; seg += 64) {
            const int p = seg + lane;
            float d = d2rn(xb[p * 3], xb[p * 3 + 1], xb[p * 3 + 2], qx, qy, qz);
            bool hit = d < r2;
            u64 mask = __ballot(hit);
            int before = (int)__popcll(mask & ((1ull << lane) - 1ull));
            if (hit && base + before < 16) ids[q][base + before] = p;
            base += (int)__popcll(mask);
            if (base >= 16) break;
        }
        if (lane == 0) {
            int cnt = base < 16 ? base : 16;
            int first = ids[q][0];
            for (int r = cnt; r < 16; ++r) ids[q][r] = first;
        }
    }
    __syncthreads();
    if constexpr (!USE_SIDE) {   // sa1: [dxyz3|feats3|pad..16]
        for (int e = t; e < TR * 16; e += 256) {
            int j = e >> 4, c = e & 15;
            int q = j >> 4, p = ids[q][j & 15];
            int bb = (q0 + q) / S;
            float v = 0.f;
            if (c < 3) v = __fsub_rn(xyz[((size_t)bb * N + p) * 3 + c], qp[q][c]);
            else if (c < 6) v = feats[((size_t)bb * N + p) * CIN + (c - 3)];
            Xs[(j * XSTR4 + ((c >> 2) ^ ((j / RT) & 3))) * 4 + (c & 3)] = v;
        }
    } else {                     // feats into Xs (float4), dxyz into side
        constexpr int C4N = CIN / 4;
        for (int e = t; e < TR * C4N; e += 256) {
            int j = e / C4N, c4 = e % C4N;
            int q = j >> 4, p = ids[q][j & 15];
            int bb = (q0 + q) / S;
            float4 v = *(const float4*)&feats[((size_t)bb * N + p) * CIN + c4 * 4];
            *(float4*)&Xs[(j * XSTR4 + (c4 ^ ((j / RT) & 3))) * 4] = v;
        }
        for (int e = t; e < TR * 3; e += 256) {
            int j = e / 3, c = e % 3;
            int q = j >> 4, p = ids[q][j & 15];
            int bb = (q0 + q) / S;
            side[e] = __fsub_rn(xyz[((size_t)bb * N + p) * 3 + c], qp[q][c]);
        }
    }
    for (int e = t; e < QPB * C2; e += 256) mp[e] = 0u;
    gemm_phase<TR, XSTR, KMAIN, (USE_SIDE ? CIN : 6), CIF, (USE_SIDE ? 3 : 0),
               C1, 0, USE_SIDE, 0, 0>(Xs, Ws, w0, g0, b0, nullptr, nullptr, 0,
                                      nullptr, side, t);
    gemm_phase<TR, XSTR, C1, C1, C1, 0, C2, 2, false, 0, 0>(
        Xs, Ws, w1, g1, b1, nullptr, nullptr, 0, mp, nullptr, t);
    __syncthreads();
    for (int e = t; e < QPB * C2; e += 256)
        ofeat[(size_t)q0 * C2 + e] = __uint_as_float(mp[e]);
}

#define SA_ARGS const float* __restrict__ xyz, const float* __restrict__ feats, \
                const int* __restrict__ fidx, \
                const float* __restrict__ w0, const float* __restrict__ g0, const float* __restrict__ b0, \
                const float* __restrict__ w1, const float* __restrict__ g1, const float* __restrict__ b1, \
                float* __restrict__ oxyz, float* __restrict__ ofeat, float r2
__global__ __launch_bounds__(256) void sa1_kernel(SA_ARGS) {
    sa_impl<4096, 256, 3, 64, 128, 64, false>(xyz, feats, fidx, w0, g0, b0, w1, g1, b1, oxyz, ofeat, r2);
}
__global__ __launch_bounds__(256) void sa2_kernel(SA_ARGS) {
    sa_impl<256, 64, 128, 128, 256, 64, true>(xyz, feats, fidx, w0, g0, b0, w1, g1, b1, oxyz, ofeat, r2);
}
__global__ __launch_bounds__(256) void sa3_kernel(SA_ARGS) {
    sa_impl<64, 16, 256, 256, 512, 16, true>(xyz, feats, fidx, w0, g0, b0, w1, g1, b1, oxyz, ofeat, r2);
}

// ---------------- FP module (fp2/fp3): wave 3-NN + interp + GEMM MLP ---------------
template <int M, int CK, int CU, int C1, int C2, int TR>
DEVI void fp_impl(const float* __restrict__ uxyz, const float* __restrict__ kxyz,
                  const float* __restrict__ ufeat, const float* __restrict__ kfeat,
                  const float* __restrict__ w0, const float* __restrict__ g0, const float* __restrict__ b0,
                  const float* __restrict__ w1, const float* __restrict__ g1, const float* __restrict__ b1,
                  float* __restrict__ out, int NU) {
    constexpr int CH = CK + CU;
    constexpr int XSTR = CH;
    constexpr int XSTR4 = XSTR / 4;
    constexpr int RT = TR / 16;
    __shared__ __align__(16) float Xs[TR * XSTR];
    __shared__ __align__(16) float Ws[2 * 128 * 12];
    __shared__ float kxs[M * 3];
    const int t = threadIdx.x, lane = t & 63, wv = t >> 6;
    const int r0 = blockIdx.x * TR;
    const int b = r0 / NU;
    for (int e = t; e < M * 3; e += 256) kxs[e] = kxyz[(size_t)b * M * 3 + e];
    __syncthreads();
    for (int j = wv; j < TR; j += 4) {
        const int r = r0 + j;
        const int sw = (j / RT) & 3;
        const float* up = uxyz + (size_t)r * 3;
        float ux = up[0], uy = up[1], uz = up[2];
        u64 a0 = ~0ull, a1 = ~0ull, a2 = ~0ull;
        for (int k = lane; k < M; k += 64) {
            float d = d2rn(kxs[k * 3], kxs[k * 3 + 1], kxs[k * 3 + 2], ux, uy, uz);
            u64 key = ((u64)__float_as_uint(d) << 32) | (unsigned)k;
            if (key < a0)      { a2 = a1; a1 = a0; a0 = key; }
            else if (key < a1) { a2 = a1; a1 = key; }
            else if (key < a2) { a2 = key; }
        }
#pragma unroll
        for (int m = 1; m < 64; m <<= 1) {
            u64 b0k = shfl_xor_u64(a0, m), b1k = shfl_xor_u64(a1, m), b2k = shfl_xor_u64(a2, m);
            u64 c0 = umin64(a0, b0k);
            u64 c1 = umin64(umax64(a0, b0k), umin64(a1, b1k));
            u64 c2 = umin64(umin64(umax64(a1, b0k), umax64(a0, b1k)), umin64(a2, b2k));
            a0 = c0; a1 = c1; a2 = c2;
        }
        int s0 = (int)(unsigned)a0, s1 = (int)(unsigned)a1, s2 = (int)(unsigned)a2;
        float d0 = __uint_as_float((unsigned)(a0 >> 32));
        float d1 = __uint_as_float((unsigned)(a1 >> 32));
        float dd2 = __uint_as_float((unsigned)(a2 >> 32));
        float wa = 1.0f / (d0 + 1e-8f), wb = 1.0f / (d1 + 1e-8f), wc = 1.0f / (dd2 + 1e-8f);
        float sum = (wa + wb) + wc;
        wa /= sum; wb /= sum; wc /= sum;
        const float* kb = kfeat + (size_t)b * M * CK;
        for (int c4 = lane; c4 < CK / 4; c4 += 64) {
            float4 va = *(const float4*)(kb + (size_t)s0 * CK + c4 * 4);
            float4 vb = *(const float4*)(kb + (size_t)s1 * CK + c4 * 4);
            float4 vc = *(const float4*)(kb + (size_t)s2 * CK + c4 * 4);
            float4 rr;
            rr.x = va.x * wa + vb.x * wb + vc.x * wc;
            rr.y = va.y * wa + vb.y * wb + vc.y * wc;
            rr.z = va.z * wa + vb.z * wb + vc.z * wc;
            rr.w = va.w * wa + vb.w * wb + vc.w * wc;
            *(float4*)&Xs[(j * XSTR4 + (c4 ^ sw)) * 4] = rr;
        }
        for (int c4 = CK / 4 + lane; c4 < CH / 4; c4 += 64) {
            float4 v = *(const float4*)&ufeat[(size_t)r * CU + (c4 * 4 - CK)];
            *(float4*)&Xs[(j * XSTR4 + (c4 ^ sw)) * 4] = v;
        }
    }
    gemm_phase<TR, XSTR, CH, CH, CH, 0, C1, 0, false, 0, 0>(
        Xs, Ws, w0, g0, b0, nullptr, nullptr, 0, nullptr, nullptr, t);
    gemm_phase<TR, XSTR, C1, C1, C1, 0, C2, 1, false, 0, C2>(
        Xs, Ws, w1, g1, b1, nullptr, out, r0, nullptr, nullptr, t);
}

#define FP_ARGS const float* __restrict__ uxyz, const float* __restrict__ kxyz, \
                const float* __restrict__ ufeat, const float* __restrict__ kfeat, \
                const float* __restrict__ w0, const float* __restrict__ g0, const float* __restrict__ b0, \
                const float* __restrict__ w1, const float* __restrict__ g1, const float* __restrict__ b1, \
                float* __restrict__ out, int NU
__global__ __launch_bounds__(256) void fp3_kernel(FP_ARGS) {
    fp_impl<16, 512, 256, 256, 256, 16>(uxyz, kxyz, ufeat, kfeat, w0, g0, b0, w1, g1, b1, out, NU);
}
__global__ __launch_bounds__(256) void fp2_kernel(FP_ARGS) {
    fp_impl<64, 256, 128, 128, 128, 16>(uxyz, kxyz, ufeat, kfeat, w0, g0, b0, w1, g1, b1, out, NU);
}

// ---------------- fp1 MLP: 3-NN (4-lane groups) + interp + 131->128->128 -----------
// output written in-place into d_out columns 0..127 (row stride 512).
__global__ __launch_bounds__(256) void fp1_mlp_kernel(
    const float* __restrict__ uxyz, const float* __restrict__ kxyz,
    const float* __restrict__ ufeat3, const float* __restrict__ kfeat,
    const float* __restrict__ w0, const float* __restrict__ g0, const float* __restrict__ b0,
    const float* __restrict__ w1, const float* __restrict__ g1, const float* __restrict__ b1,
    float* __restrict__ out) {
    constexpr int TR = 128, M = 256, CK = 128;
    __shared__ __align__(16) float Xs[TR * 128];     // 64 KiB
    __shared__ __align__(16) float Ws[2 * 128 * 12]; // 12 KiB
    __shared__ float side[TR * 3];
    __shared__ float wgt2[TR * 2];
    __shared__ unsigned pidx[TR];
    const int t = threadIdx.x;
    const int r0 = blockIdx.x * TR;
    const int b = r0 >> 12;   // NU = 4096
    // side = raw 3-channel features (contiguous copy)
    for (int e = t; e < TR * 3; e += 256) side[e] = ufeat3[(size_t)r0 * 3 + e];
    // 3-NN: 4-lane group per row (exact order stats, same keys/merge as before)
    const int g = t >> 2, sub = t & 3;
    const float* kb3 = kxyz + (size_t)b * M * 3;
    for (int row = g; row < TR; row += 64) {
        const float* up = uxyz + (size_t)(r0 + row) * 3;
        float ux = up[0], uy = up[1], uz = up[2];
        u64 a0 = ~0ull, a1 = ~0ull, a2 = ~0ull;
        for (int k = sub; k < M; k += 4) {
            float d = d2rn(kb3[k * 3], kb3[k * 3 + 1], kb3[k * 3 + 2], ux, uy, uz);
            u64 key = ((u64)__float_as_uint(d) << 32) | (unsigned)k;
            if (key < a0)      { a2 = a1; a1 = a0; a0 = key; }
            else if (key < a1) { a2 = a1; a1 = key; }
            else if (key < a2) { a2 = key; }
        }
#pragma unroll
        for (int m = 1; m < 4; m <<= 1) {
            u64 b0k = shfl_xor_u64(a0, m), b1k = shfl_xor_u64(a1, m), b2k = shfl_xor_u64(a2, m);
            u64 c0 = umin64(a0, b0k);
            u64 c1 = umin64(umax64(a0, b0k), umin64(a1, b1k));
            u64 c2 = umin64(umin64(umax64(a1, b0k), umax64(a0, b1k)), umin64(a2, b2k));
            a0 = c0; a1 = c1; a2 = c2;
        }
        if (sub == 0) {
            unsigned s0 = (unsigned)a0 & 255u, s1 = (unsigned)a1 & 255u, s2 = (unsigned)a2 & 255u;
            float d0 = __uint_as_float((unsigned)(a0 >> 32));
            float d1 = __uint_as_float((unsigned)(a1 >> 32));
            float dd2 = __uint_as_float((unsigned)(a2 >> 32));
            float wa = 1.0f / (d0 + 1e-8f), wb = 1.0f / (d1 + 1e-8f), wc = 1.0f / (dd2 + 1e-8f);
            float sum = (wa + wb) + wc;
            wa /= sum; wb /= sum;
            pidx[row] = s0 | (s1 << 8) | (s2 << 16);
            wgt2[row * 2] = wa; wgt2[row * 2 + 1] = wb;
        }
    }
    __syncthreads();
    // interp fill, block-wide (Xs swizzled by (row/8)&3)
    const float* kfb = kfeat + (size_t)b * M * CK;
    for (int e = t; e < TR * 32; e += 256) {
        int j = e >> 5, c4 = e & 31;
        unsigned u = pidx[j];
        int s0 = u & 255, s1 = (u >> 8) & 255, s2 = (u >> 16) & 255;
        float wa = wgt2[j * 2], wb = wgt2[j * 2 + 1], wc = 1.0f - wa - wb;
        float4 va = *(const float4*)(kfb + (size_t)s0 * CK + c4 * 4);
        float4 vb = *(const float4*)(kfb + (size_t)s1 * CK + c4 * 4);
        float4 vc = *(const float4*)(kfb + (size_t)s2 * CK + c4 * 4);
        float4 rr;
        rr.x = va.x * wa + vb.x * wb + vc.x * wc;
        rr.y = va.y * wa + vb.y * wb + vc.y * wc;
        rr.z = va.z * wa + vb.z * wb + vc.z * wc;
        rr.w = va.w * wa + vb.w * wb + vc.w * wc;
        *(float4*)&Xs[(j * 32 + (c4 ^ ((j >> 3) & 3))) * 4] = rr;
    }
    gemm_phase<TR, 128, 128, 128, 131, 0, 128, 0, true, 128, 0>(
        Xs, Ws, w0, g0, b0, nullptr, nullptr, 0, nullptr, side, t);
    gemm_phase<TR, 128, 128, 128, 128, 0, 128, 1, false, 0, 512>(
        Xs, Ws, w1, g1, b1, nullptr, out, r0, nullptr, nullptr, t);
}

// ---------------- final GEMM: [65536,128] x [512,128]^T +bias+BN+ReLU, in-place ----
// SELF-CONTAINED blocks: each block owns 128 rows exclusively; X tile staged to LDS
// once, then all 4 column-tiles computed (no cross-block read-after-write hazard).
__global__ __launch_bounds__(256) void fin_kernel(
    float* io,   // d_out: X in cols 0..127 (stride 512); all 512 cols written
    const float* __restrict__ fw, const float* __restrict__ fb,
    const float* __restrict__ fg, const float* __restrict__ fbe) {
    __shared__ __align__(16) float Xs[128 * 128];     // 64 KiB, swizzled
    __shared__ __align__(16) float Ws[2 * 128 * 12];  // 12 KiB dbuf
    const int t = threadIdx.x, tx = t & 15, ty = t >> 4;
    const int r0 = blockIdx.x * 128;
    const int swz = ty & 3;
    // stage X tile (cols 0..127) into LDS, float4-swizzled by (row/8)&3
    for (int e = t; e < 128 * 32; e += 256) {
        int j = e >> 5, c4 = e & 31;
        float4 v = *(const float4*)&io[(size_t)(r0 + j) * 512 + c4 * 4];
        *(float4*)&Xs[(j * 32 + (c4 ^ ((j >> 3) & 3))) * 4] = v;
    }
    for (int nt = 0; nt < 4; ++nt) {
        const int c0 = nt * 128;
        float acc[8][8];
#pragma unroll
        for (int r = 0; r < 8; ++r)
#pragma unroll
            for (int i = 0; i < 8; ++i) acc[r][i] = 0.f;
        float wpre[4];
#pragma unroll
        for (int i = 0; i < 4; ++i) {   // prefetch W chunk 0
            int e = t + 256 * i, row = e >> 3, kk = e & 7;
            wpre[i] = fw[(size_t)(c0 + row) * 128 + kk];
        }
#pragma unroll
        for (int i = 0; i < 4; ++i) {   // stage -> buf0 (per-thread-disjoint slots)
            int e = t + 256 * i;
            Ws[(e >> 3) * 12 + (e & 7)] = wpre[i];
        }
        for (int kc = 0; kc < 16; ++kc) {
            const int buf = kc & 1;
            __syncthreads();   // X staged (nt=0,kc=0) / Ws[buf] staged, readers done
            if (kc < 15) {
                const int kn = (kc + 1) * 8;
#pragma unroll
                for (int i = 0; i < 4; ++i) {
                    int e = t + 256 * i, row = e >> 3, kk = e & 7;
                    wpre[i] = fw[(size_t)(c0 + row) * 128 + kn + kk];
                }
            }
            const float* wsb = Ws + buf * 1536;
#pragma unroll
            for (int k4i = 0; k4i < 2; ++k4i) {
                const int c4 = kc * 2 + k4i;
                float4 wv[8];
#pragma unroll
                for (int i = 0; i < 8; ++i)
                    wv[i] = *(const float4*)&wsb[(tx + 16 * i) * 12 + k4i * 4];
                float4 xv[8];
#pragma unroll
                for (int r = 0; r < 8; ++r)
                    xv[r] = *(const float4*)&Xs[((ty * 8 + r) * 32 + (c4 ^ swz)) * 4];
#pragma unroll
                for (int r = 0; r < 8; ++r)
#pragma unroll
                    for (int i = 0; i < 8; ++i) {
                        acc[r][i] = fmaf(xv[r].x, wv[i].x, acc[r][i]);
                        acc[r][i] = fmaf(xv[r].y, wv[i].y, acc[r][i]);
                        acc[r][i] = fmaf(xv[r].z, wv[i].z, acc[r][i]);
                        acc[r][i] = fmaf(xv[r].w, wv[i].w, acc[r][i]);
                    }
            }
            if (kc < 15) {   // write-late into other buffer
                float* wsn = Ws + (buf ^ 1) * 1536;
#pragma unroll
                for (int i = 0; i < 4; ++i) {
                    int e = t + 256 * i;
                    wsn[(e >> 3) * 12 + (e & 7)] = wpre[i];
                }
            }
        }
#pragma unroll
        for (int i = 0; i < 8; ++i) {
            int c = c0 + tx + 16 * i;
            float bia = fb[c], sc = fg[c] * BN_INV_F, be = fbe[c];
#pragma unroll
            for (int r = 0; r < 8; ++r) {
                float val = fmaxf(fmaf(acc[r][i] + bia, sc, be), 0.f);
                io[(size_t)(r0 + ty * 8 + r) * 512 + c] = val;
            }
        }
    }
}

extern "C" void kernel_launch(void* const* d_in, const int* in_sizes, int n_in,
                              void* d_out, int out_size, void* d_ws, size_t ws_size,
                              hipStream_t stream) {
    (void)in_sizes; (void)n_in; (void)out_size; (void)ws_size;
    const float* xyz   = (const float*)d_in[0];
    const float* feats = (const float*)d_in[1];  // [B,N,3] point-major
    const float* sa1_w0 = (const float*)d_in[2];
    const float* sa1_g0 = (const float*)d_in[3];
    const float* sa1_b0 = (const float*)d_in[4];
    const float* sa1_w1 = (const float*)d_in[5];
    const float* sa1_g1 = (const float*)d_in[6];
    const float* sa1_b1 = (const float*)d_in[7];
    const float* sa2_w0 = (const float*)d_in[8];
    const float* sa2_g0 = (const float*)d_in[9];
    const float* sa2_b0 = (const float*)d_in[10];
    const float* sa2_w1 = (const float*)d_in[11];
    const float* sa2_g1 = (const float*)d_in[12];
    const float* sa2_b1 = (const float*)d_in[13];
    const float* sa3_w0 = (const float*)d_in[14];
    const float* sa3_g0 = (const float*)d_in[15];
    const float* sa3_b0 = (const float*)d_in[16];
    const float* sa3_w1 = (const float*)d_in[17];
    const float* sa3_g1 = (const float*)d_in[18];
    const float* sa3_b1 = (const float*)d_in[19];
    const float* fp3_w0 = (const float*)d_in[20];
    const float* fp3_g0 = (const float*)d_in[21];
    const float* fp3_b0 = (const float*)d_in[22];
    const float* fp3_w1 = (const float*)d_in[23];
    const float* fp3_g1 = (const float*)d_in[24];
    const float* fp3_b1 = (const float*)d_in[25];
    const float* fp2_w0 = (const float*)d_in[26];
    const float* fp2_g0 = (const float*)d_in[27];
    const float* fp2_b0 = (const float*)d_in[28];
    const float* fp2_w1 = (const float*)d_in[29];
    const float* fp2_g1 = (const float*)d_in[30];
    const float* fp2_b1 = (const float*)d_in[31];
    const float* fp1_w0 = (const float*)d_in[32];
    const float* fp1_g0 = (const float*)d_in[33];
    const float* fp1_b0 = (const float*)d_in[34];
    const float* fp1_w1 = (const float*)d_in[35];
    const float* fp1_g1 = (const float*)d_in[36];
    const float* fp1_b1 = (const float*)d_in[37];
    const float* fin_w  = (const float*)d_in[38];
    const float* fin_b  = (const float*)d_in[39];
    const float* fin_g  = (const float*)d_in[40];
    const float* fin_be = (const float*)d_in[41];

    float* ws = (float*)d_ws;
    float* l1x  = ws;                 // 16*256*3    = 12288
    float* l1f  = l1x + 12288;        // 16*256*128  = 524288
    float* l2x  = l1f + 524288;       // 16*64*3     = 3072
    float* l2f  = l2x + 3072;         // 16*64*256   = 262144
    float* l3x  = l2f + 262144;       // 16*16*3     = 768
    float* l3f  = l3x + 768;          // 16*16*512   = 131072
    float* l2fb = l3f + 131072;       // 16*64*256   = 262144
    float* l1fb = l2fb + 262144;      // 16*256*128  = 524288
    int* fidx1 = (int*)(l1fb + 524288);  // 16*256
    int* fidx2 = fidx1 + 4096;           // 16*64
    int* fidx3 = fidx2 + 1024;           // 16*16

    const float R2_1 = (float)(0.04 * 0.04);
    const float R2_2 = (float)(0.08 * 0.08);
    const float R2_3 = (float)(0.16 * 0.16);

    fps1_kernel<<<16, 256, 0, stream>>>(xyz, fidx1);
    sa1_kernel<<<1024, 256, 0, stream>>>(
        xyz, feats, fidx1, sa1_w0, sa1_g0, sa1_b0, sa1_w1, sa1_g1, sa1_b1,
        l1x, l1f, R2_1);

    fps2_kernel<<<16, 64, 0, stream>>>(l1x, fidx2);
    sa2_kernel<<<256, 256, 0, stream>>>(
        l1x, l1f, fidx2, sa2_w0, sa2_g0, sa2_b0, sa2_w1, sa2_g1, sa2_b1,
        l2x, l2f, R2_2);

    fps3_kernel<<<16, 64, 0, stream>>>(l2x, fidx3);
    sa3_kernel<<<256, 256, 0, stream>>>(
        l2x, l2f, fidx3, sa3_w0, sa3_g0, sa3_b0, sa3_w1, sa3_g1, sa3_b1,
        l3x, l3f, R2_3);

    // FP3: unk=l2 (1024 rows), kn=l3 (M=16), 768 -> 256 -> 256
    fp3_kernel<<<64, 256, 0, stream>>>(
        l2x, l3x, l2f, l3f, fp3_w0, fp3_g0, fp3_b0, fp3_w1, fp3_g1, fp3_b1,
        l2fb, 64);

    // FP2: unk=l1 (4096 rows), kn=l2 (M=64), 384 -> 128 -> 128
    fp2_kernel<<<256, 256, 0, stream>>>(
        l1x, l2x, l1f, l2fb, fp2_w0, fp2_g0, fp2_b0, fp2_w1, fp2_g1, fp2_b1,
        l1fb, 256);

    // FP1 MLP: 131 -> 128 -> 128 into d_out cols 0..127 (stride 512)
    fp1_mlp_kernel<<<512, 256, 0, stream>>>(
        xyz, l1x, feats, l1fb, fp1_w0, fp1_g0, fp1_b0, fp1_w1, fp1_g1, fp1_b1,
        (float*)d_out);

    // final 128 -> 512 (+bias+BN+ReLU), in-place, self-contained blocks
    fin_kernel<<<512, 256, 0, stream>>>(
        (float*)d_out, fin_w, fin_b, fin_g, fin_be);
}